// Round 9
// baseline (764.779 us; speedup 1.0000x reference)
//
#include <hip/hip_runtime.h>
#include <hip/hip_fp16.h>

#define NN 100000
#define EE 1200000
#define DD 64
#define CC 40
#define KK 16
#define BSZ 196                          // nodes per sort bucket
#define NBK 512                          // buckets (512*196 = 100352 >= NN)
#define TCAP 3072                        // tmp capacity per bucket (mean 2352, ~15 sigma)
#define EPB 4096                         // edges per phase-A block
#define ABLK ((EE + EPB - 1) / EPB)      // 293
#define PL1 (NN * 4)                     // float4-index offset of plane1 in an x buffer

struct __align__(8) ERec { int c; float w; };

// ---------- cursor init: cursor[b] = b*TCAP ----------
__global__ __launch_bounds__(512) void curinit_kernel(int* __restrict__ cursor) {
    int b = threadIdx.x;
    if (b < NBK) cursor[b] = b * TCAP;
}

// ---------- sort phase A: LDS-bin 4096 edges into 512 buckets, write runs ----------
__global__ __launch_bounds__(256) void sortA_kernel(const int* __restrict__ src,
                                                    const int* __restrict__ dst,
                                                    int* __restrict__ cursor,
                                                    int2* __restrict__ tmp) {
    __shared__ int2 stg[EPB];                 // 32KB
    __shared__ int hist[NBK], loff[NBK], lcur[NBK], gbase[NBK];  // 8KB
    int t = threadIdx.x;
    long e0 = (long)blockIdx.x * EPB;
    int n = (int)((EE - e0 < EPB) ? (EE - e0) : EPB);
    for (int j = t; j < NBK; j += 256) hist[j] = 0;
    __syncthreads();
    int d[16], sx[16];
#pragma unroll
    for (int j = 0; j < 16; ++j) {
        int i = t + j * 256;
        if (i < n) {
            d[j] = dst[e0 + i];
            sx[j] = src[e0 + i];
            atomicAdd(&hist[d[j] / BSZ], 1);
        } else d[j] = -1;
    }
    __syncthreads();
    int c0 = hist[2 * t], c1 = hist[2 * t + 1];
    int s2 = c0 + c1;
    __syncthreads();
    loff[t] = s2;
    __syncthreads();
    for (int off = 1; off < 256; off <<= 1) {
        int u = (t >= off) ? loff[t - off] : 0;
        __syncthreads();
        loff[t] += u;
        __syncthreads();
    }
    int excl = loff[t] - s2;
    __syncthreads();
    loff[2 * t] = excl;          loff[2 * t + 1] = excl + c0;
    lcur[2 * t] = excl;          lcur[2 * t + 1] = excl + c0;
    gbase[2 * t]     = atomicAdd(&cursor[2 * t], c0);
    gbase[2 * t + 1] = atomicAdd(&cursor[2 * t + 1], c1);
    __syncthreads();
#pragma unroll
    for (int j = 0; j < 16; ++j) {
        if (d[j] >= 0) {
            int b = d[j] / BSZ;
            int p = atomicAdd(&lcur[b], 1);
            stg[p] = make_int2(d[j], sx[j]);
        }
    }
    __syncthreads();
    for (int i = t; i < n; i += 256) {
        int2 r = stg[i];
        int b = r.x / BSZ;
        int pos = gbase[b] + (i - loff[b]);
        if (pos < (b + 1) * TCAP) tmp[pos] = r;  // overflow guard (never hit, 15 sigma)
    }
}

// ---------- bucket-base scan ----------
__global__ __launch_bounds__(512) void bscan_kernel(const int* __restrict__ cursor,
                                                    int* __restrict__ bbase,
                                                    int* __restrict__ row_ptr) {
    __shared__ int sm[512];
    int t = threadIdx.x;
    int v = (t < NBK) ? (cursor[t] - t * TCAP) : 0;
    sm[t] = v;
    __syncthreads();
    for (int off = 1; off < 512; off <<= 1) {
        int u = (t >= off) ? sm[t - off] : 0;
        __syncthreads();
        sm[t] += u;
        __syncthreads();
    }
    if (t < NBK) bbase[t] = sm[t] - v;
    if (t == 511) row_ptr[NN] = sm[511];  // == EE
}

// ---------- sort phase B: counting sort within bucket; also emits deg + 64-bin
// global degree histogram (block-aggregated -> few device atomics) ----------
__global__ __launch_bounds__(256) void sortB_kernel(const int2* __restrict__ tmp,
                                                    const int* __restrict__ cursor,
                                                    const int* __restrict__ bbase,
                                                    float* __restrict__ dinv,
                                                    int* __restrict__ deg,
                                                    int* __restrict__ dbins,
                                                    int* __restrict__ row_ptr,
                                                    int2* __restrict__ er2) {
    __shared__ int2 se[TCAP];     // 24KB
    __shared__ int2 so[TCAP];     // 24KB
    __shared__ int hist[256], lcur[256];
    __shared__ int dh[64];
    int b = blockIdx.x;
    int n0 = b * BSZ;
    if (n0 >= NN) return;
    int n1 = n0 + BSZ; if (n1 > NN) n1 = NN;
    int nb = n1 - n0;
    int t = threadIdx.x;
    int cnt = cursor[b] - b * TCAP;
    int base = bbase[b];
    hist[t] = 0;
    __syncthreads();
    for (int i = t; i < cnt; i += 256) {
        int2 r = tmp[b * TCAP + i];
        se[i] = r;
        atomicAdd(&hist[r.x - n0], 1);
    }
    __syncthreads();
    if (t < nb) {
        dinv[n0 + t] = rsqrtf((float)(hist[t] + 1));  // +1 self-loop
        deg[n0 + t] = hist[t];
    }
    if (t < 64) dh[t] = 0;
    int v = hist[t];
    lcur[t] = v;
    __syncthreads();
    if (t < nb) atomicAdd(&dh[v < 63 ? v : 63], 1);
    __syncthreads();
    if (t < 64 && dh[t] > 0) atomicAdd(&dbins[t], dh[t]);
    for (int off = 1; off < 256; off <<= 1) {
        int u = (t >= off) ? lcur[t - off] : 0;
        __syncthreads();
        lcur[t] += u;
        __syncthreads();
    }
    int excl = lcur[t] - v;
    __syncthreads();
    lcur[t] = excl;
    if (t < nb) row_ptr[n0 + t] = base + excl;
    __syncthreads();
    for (int i = t; i < cnt; i += 256) {
        int2 r = se[i];
        int ln = r.x - n0;
        int pos = atomicAdd(&lcur[ln], 1);
        so[pos] = make_int2(r.y, r.x);  // (src, dst)
    }
    __syncthreads();
    for (int i = t; i < cnt; i += 256) er2[base + i] = so[i];  // coalesced
}

// ---------- degree-bin exclusive scan (64 bins) ----------
__global__ __launch_bounds__(64) void dscan_kernel(const int* __restrict__ dbins,
                                                   int* __restrict__ dcur) {
    __shared__ int sm[64];
    int t = threadIdx.x;
    int v = dbins[t];
    sm[t] = v;
    __syncthreads();
    for (int off = 1; off < 64; off <<= 1) {
        int u = (t >= off) ? sm[t - off] : 0;
        __syncthreads();
        sm[t] += u;
        __syncthreads();
    }
    dcur[t] = sm[t] - v;
}

// ---------- degree-rank assignment: degperm[rank] = node, degree-sorted ----------
__global__ __launch_bounds__(256) void dassign_kernel(const int* __restrict__ deg,
                                                      int* __restrict__ dcur,
                                                      int* __restrict__ degperm) {
    __shared__ int lh[64], lbase[64];
    int t = threadIdx.x;
    int i = blockIdx.x * 256 + t;
    if (t < 64) lh[t] = 0;
    __syncthreads();
    int d = -1, lo = 0;
    if (i < NN) {
        d = deg[i]; if (d > 63) d = 63;
        lo = atomicAdd(&lh[d], 1);
    }
    __syncthreads();
    if (t < 64 && lh[t] > 0) lbase[t] = atomicAdd(&dcur[t], lh[t]);
    __syncthreads();
    if (i < NN) degperm[lbase[d] + lo] = i;
}

// ---------- weight fill ----------
__global__ __launch_bounds__(256) void wfill_kernel(const int2* __restrict__ er2,
                                                    const float* __restrict__ dinv,
                                                    int2* __restrict__ er) {
    int i = blockIdx.x * 256 + threadIdx.x;
    if (i >= EE) return;
    int2 r = er2[i];
    float w = dinv[r.y] * dinv[r.x];
    er[i] = make_int2(r.x, __float_as_int(w));
}

// ---------- projection: y0 = feat @ W^T (LDS-tiled, coalesced) ----------
// 64 nodes/block; 4 threads/node x 10 fp32 accumulators; feat + W staged in
// padded LDS (stride 68 floats: 16B-aligned b128 + spread banks).
__global__ __launch_bounds__(256) void proj_kernel(const float4* __restrict__ feat4,
                                                   const float* __restrict__ W,
                                                   float4* __restrict__ y0) {
    __shared__ float smW[CC * 68];   // 10.9KB
    __shared__ float smF[64 * 68];   // 17.4KB
    __shared__ float smO[64 * 42];   // 10.8KB
    int t = threadIdx.x;
    for (int j = t; j < CC * 16; j += 256) {
        int c = j >> 4, q = j & 15;
        *(float4*)(smW + c * 68 + q * 4) = ((const float4*)W)[j];
    }
    int n0 = blockIdx.x * 64;
    for (int j = t; j < 64 * 16; j += 256) {
        int r = j >> 4, q = j & 15;
        if (n0 + r < NN)
            *(float4*)(smF + r * 68 + q * 4) = feat4[(size_t)(n0 + r) * 16 + q];
    }
    __syncthreads();
    int ln = t >> 2, c0 = (t & 3) * 10;
    int node = n0 + ln;
    float acc[10];
#pragma unroll
    for (int c = 0; c < 10; ++c) acc[c] = 0.f;
    if (node < NN) {
#pragma unroll
        for (int db = 0; db < 16; ++db) {
            float4 fv = *(const float4*)(smF + ln * 68 + db * 4);
#pragma unroll
            for (int c = 0; c < 10; ++c) {
                float4 wv = *(const float4*)(smW + (c0 + c) * 68 + db * 4);
                acc[c] = fmaf(fv.x, wv.x, acc[c]);
                acc[c] = fmaf(fv.y, wv.y, acc[c]);
                acc[c] = fmaf(fv.z, wv.z, acc[c]);
                acc[c] = fmaf(fv.w, wv.w, acc[c]);
            }
        }
    }
#pragma unroll
    for (int c = 0; c < 10; ++c) smO[ln * 42 + c0 + c] = acc[c];
    __syncthreads();
    for (int j = t; j < 64 * 5; j += 256) {
        int r = j / 5, q = j - r * 5;
        if (n0 + r < NN) {
            const float* s = smO + r * 42 + q * 8;
            float4 ov;
            __half2* op = (__half2*)&ov;
            op[0] = __floats2half2_rn(s[0], s[1]);
            op[1] = __floats2half2_rn(s[2], s[3]);
            op[2] = __floats2half2_rn(s[4], s[5]);
            op[3] = __floats2half2_rn(s[6], s[7]);
            y0[(q < 4) ? ((size_t)(n0 + r) * 4 + q) : (size_t)(PL1 + n0 + r)] = ov;
        }
    }
}

// ---------- fused SpMM in C-space (40 dims, fp16, dual-plane) + h-update ----------
// Nodes processed in degree-sorted order (degperm) so each wave's 12 nodes have
// ~equal degree -> no divergence waste. Storage stays in original node space
// (plane0 rows are full 64B lines -> scattered writes don't amplify).
// mode: 0 none; 1 h init (j==10); 2 h accum; 3 final: out = h+FC*y0+b -> d_out
__global__ __launch_bounds__(256) void spmm_step(
    const float4* __restrict__ x, float4* __restrict__ x_out,
    const float4* __restrict__ y0, float4* __restrict__ h4,
    float* __restrict__ outp, const float* __restrict__ bias,
    const int* __restrict__ row_ptr, const ERec* __restrict__ er,
    const float* __restrict__ dinv, const int* __restrict__ degperm, int mode) {
    int tid = blockIdx.x * 256 + threadIdx.x;
    int wid = tid >> 6;
    int lane = tid & 63;
    int nw = lane / 5;         // node within wave, 12 = idle
    int li = lane - nw * 5;    // 0..4, owns dims [8li, 8li+8)
    int g0 = wid * 12 + nw;
    if (nw >= 12 || g0 >= NN) return;
    int g = degperm[g0];
    int beg = row_ptr[g], end = row_ptr[g + 1];
    float di = dinv[g];
    float w0 = di * di;
    int m = (li < 4) ? 4 : 1;
    int a = (li < 4) ? li : PL1;
    int base = g * m + a;
    float4 sv = x[base];
    float a0, a1, a2, a3, a4, a5, a6, a7;
    {
        const __half2* hp = (const __half2*)&sv;
        float2 f0 = __half22float2(hp[0]), f1 = __half22float2(hp[1]);
        float2 f2 = __half22float2(hp[2]), f3 = __half22float2(hp[3]);
        a0 = w0 * f0.x; a1 = w0 * f0.y; a2 = w0 * f1.x; a3 = w0 * f1.y;
        a4 = w0 * f2.x; a5 = w0 * f2.y; a6 = w0 * f3.x; a7 = w0 * f3.y;
    }
#define ACC8(R, V)                                                          \
    {                                                                       \
        const __half2* hp = (const __half2*)&(V);                           \
        float2 f0 = __half22float2(hp[0]), f1 = __half22float2(hp[1]);      \
        float2 f2 = __half22float2(hp[2]), f3 = __half22float2(hp[3]);      \
        a0 = fmaf((R).w, f0.x, a0); a1 = fmaf((R).w, f0.y, a1);             \
        a2 = fmaf((R).w, f1.x, a2); a3 = fmaf((R).w, f1.y, a3);             \
        a4 = fmaf((R).w, f2.x, a4); a5 = fmaf((R).w, f2.y, a5);             \
        a6 = fmaf((R).w, f3.x, a6); a7 = fmaf((R).w, f3.y, a7);             \
    }
    int e = beg;
    int e4 = beg + ((end - beg) & ~3);
    for (; e < e4; e += 4) {
        ERec r0 = er[e], r1 = er[e + 1], r2 = er[e + 2], r3 = er[e + 3];
        float4 v0 = x[r0.c * m + a];
        float4 v1 = x[r1.c * m + a];
        float4 v2 = x[r2.c * m + a];
        float4 v3 = x[r3.c * m + a];
        ACC8(r0, v0); ACC8(r1, v1); ACC8(r2, v2); ACC8(r3, v3);
    }
    for (; e < end; ++e) {
        ERec r = er[e];
        float4 v = x[r.c * m + a];
        ACC8(r, v);
    }
#undef ACC8
    if (mode != 3) {
        float4 ov;
        __half2* op = (__half2*)&ov;
        op[0] = __floats2half2_rn(a0, a1);
        op[1] = __floats2half2_rn(a2, a3);
        op[2] = __floats2half2_rn(a4, a5);
        op[3] = __floats2half2_rn(a6, a7);
        x_out[base] = ov;
    }
    if (mode) {
        int hb = g * 10 + li * 2;
        float4 h0, h1;
        if (mode == 1) {  // init: h was 0
            h0.x = 0.95f * a0 * (1.0f / 16.0f); h0.y = 0.95f * a1 * (1.0f / 16.0f);
            h0.z = 0.95f * a2 * (1.0f / 16.0f); h0.w = 0.95f * a3 * (1.0f / 16.0f);
            h1.x = 0.95f * a4 * (1.0f / 16.0f); h1.y = 0.95f * a5 * (1.0f / 16.0f);
            h1.z = 0.95f * a6 * (1.0f / 16.0f); h1.w = 0.95f * a7 * (1.0f / 16.0f);
        } else {
            h0 = h4[hb]; h1 = h4[hb + 1];
            h0.x = (h0.x + 0.95f * a0) * (1.0f / 16.0f);
            h0.y = (h0.y + 0.95f * a1) * (1.0f / 16.0f);
            h0.z = (h0.z + 0.95f * a2) * (1.0f / 16.0f);
            h0.w = (h0.w + 0.95f * a3) * (1.0f / 16.0f);
            h1.x = (h1.x + 0.95f * a4) * (1.0f / 16.0f);
            h1.y = (h1.y + 0.95f * a5) * (1.0f / 16.0f);
            h1.z = (h1.z + 0.95f * a6) * (1.0f / 16.0f);
            h1.w = (h1.w + 0.95f * a7) * (1.0f / 16.0f);
        }
        if (mode == 3) {
            const float FC = 0.05f / 15.0f;  // analytic sum of all 16 y0 terms
            float4 yv = y0[base];
            const __half2* yp = (const __half2*)&yv;
            float2 y01 = __half22float2(yp[0]), y23 = __half22float2(yp[1]);
            float2 y45 = __half22float2(yp[2]), y67 = __half22float2(yp[3]);
            const float4* b4 = (const float4*)(bias + li * 8);
            float4 bb0 = b4[0], bb1 = b4[1];
            h0.x = fmaf(FC, y01.x, h0.x) + bb0.x;
            h0.y = fmaf(FC, y01.y, h0.y) + bb0.y;
            h0.z = fmaf(FC, y23.x, h0.z) + bb0.z;
            h0.w = fmaf(FC, y23.y, h0.w) + bb0.w;
            h1.x = fmaf(FC, y45.x, h1.x) + bb1.x;
            h1.y = fmaf(FC, y45.y, h1.y) + bb1.y;
            h1.z = fmaf(FC, y67.x, h1.z) + bb1.z;
            h1.w = fmaf(FC, y67.y, h1.w) + bb1.w;
            float4* op = (float4*)(outp + (size_t)g * CC + li * 8);
            op[0] = h0; op[1] = h1;
        } else {
            h4[hb] = h0; h4[hb + 1] = h1;
        }
    }
}

extern "C" void kernel_launch(void* const* d_in, const int* in_sizes, int n_in,
                              void* d_out, int out_size, void* d_ws, size_t ws_size,
                              hipStream_t stream) {
    const float* feat = (const float*)d_in[0];
    const float* W    = (const float*)d_in[1];
    const float* b    = (const float*)d_in[2];
    const int*   src  = (const int*)d_in[3];
    const int*   dst  = (const int*)d_in[4];
    float* out = (float*)d_out;

    char* p = (char*)d_ws;
    auto alloc = [&](size_t bytes) {
        char* r = p;
        p += (bytes + 255) & ~(size_t)255;
        return r;
    };
    float*   dinv    = (float*)alloc((size_t)NN * sizeof(float));
    int*     deg     = (int*)alloc((size_t)NN * sizeof(int));
    int*     degperm = (int*)alloc((size_t)NN * sizeof(int));
    int*     row_ptr = (int*)alloc((size_t)(NN + 1) * sizeof(int));
    int*     cursor  = (int*)alloc((size_t)NBK * sizeof(int));
    int*     bbase   = (int*)alloc((size_t)NBK * sizeof(int));
    int*     dbins   = (int*)alloc(64 * sizeof(int));
    int*     dcur    = (int*)alloc(64 * sizeof(int));
    int2*    tmp     = (int2*)alloc((size_t)NBK * TCAP * sizeof(int2));  // 12.6MB
    int2*    er2     = (int2*)alloc((size_t)EE * sizeof(int2));          // 9.6MB
    int2*    er      = (int2*)alloc((size_t)EE * sizeof(int2));          // 9.6MB
    float4*  y0      = (float4*)alloc((size_t)NN * 5 * sizeof(float4));  // 8MB
    float4*  xa      = (float4*)alloc((size_t)NN * 5 * sizeof(float4));  // 8MB
    float4*  xb      = (float4*)alloc((size_t)NN * 5 * sizeof(float4));  // 8MB
    float4*  h       = (float4*)alloc((size_t)NN * 10 * sizeof(float4)); // 16MB

    hipMemsetAsync(dbins, 0, 64 * sizeof(int), stream);

    curinit_kernel<<<1, 512, 0, stream>>>(cursor);
    sortA_kernel<<<ABLK, 256, 0, stream>>>(src, dst, cursor, tmp);
    bscan_kernel<<<1, 512, 0, stream>>>(cursor, bbase, row_ptr);
    sortB_kernel<<<NBK, 256, 0, stream>>>(tmp, cursor, bbase, dinv, deg, dbins,
                                          row_ptr, er2);
    dscan_kernel<<<1, 64, 0, stream>>>(dbins, dcur);
    dassign_kernel<<<(NN + 255) / 256, 256, 0, stream>>>(deg, dcur, degperm);
    wfill_kernel<<<(EE + 255) / 256, 256, 0, stream>>>(er2, dinv, er);
    proj_kernel<<<(NN + 63) / 64, 256, 0, stream>>>((const float4*)feat, W, y0);

    // waves = ceil(NN/12) = 8334 -> blocks of 4 waves
    const int SPMM_BLOCKS = (8334 + 3) / 4;  // 2084
    const float4* xs = y0;
    float4* xd = xa;
    for (int j = 0; j < KK; ++j) {
        int mode = (j < 10) ? 0 : ((j == 10) ? 1 : ((j == KK - 1) ? 3 : 2));
        spmm_step<<<SPMM_BLOCKS, 256, 0, stream>>>(xs, xd, y0, h, out, b, row_ptr,
                                                   (const ERec*)er, dinv, degperm, mode);
        xs = xd;
        xd = (xd == xa) ? xb : xa;
    }
}

// Round 10
// 612.927 us; speedup vs baseline: 1.2477x; 1.2477x over previous
//
#include <hip/hip_runtime.h>
#include <hip/hip_fp16.h>

#define NN 100000
#define EE 1200000
#define DD 64
#define CC 40
#define KK 16
#define BSZ 196                          // nodes per sort bucket
#define NBK 512                          // buckets (512*196 = 100352 >= NN)
#define TCAP 3072                        // tmp capacity per bucket (mean 2352, ~15 sigma)
#define EPB 4096                         // edges per phase-A block
#define ABLK ((EE + EPB - 1) / EPB)      // 293
#define PL1 (NN * 4)                     // float4-index offset of plane1 in an x buffer

struct __align__(8) ERec { int c; float w; };

// ---------- cursor init: cursor[b] = b*TCAP ----------
__global__ __launch_bounds__(512) void curinit_kernel(int* __restrict__ cursor) {
    int b = threadIdx.x;
    if (b < NBK) cursor[b] = b * TCAP;
}

// ---------- sort phase A: LDS-bin 4096 edges into 512 buckets, write runs ----------
__global__ __launch_bounds__(256) void sortA_kernel(const int* __restrict__ src,
                                                    const int* __restrict__ dst,
                                                    int* __restrict__ cursor,
                                                    int2* __restrict__ tmp) {
    __shared__ int2 stg[EPB];                 // 32KB
    __shared__ int hist[NBK], loff[NBK], lcur[NBK], gbase[NBK];  // 8KB
    int t = threadIdx.x;
    long e0 = (long)blockIdx.x * EPB;
    int n = (int)((EE - e0 < EPB) ? (EE - e0) : EPB);
    for (int j = t; j < NBK; j += 256) hist[j] = 0;
    __syncthreads();
    int d[16], sx[16];
#pragma unroll
    for (int j = 0; j < 16; ++j) {
        int i = t + j * 256;
        if (i < n) {
            d[j] = dst[e0 + i];
            sx[j] = src[e0 + i];
            atomicAdd(&hist[d[j] / BSZ], 1);
        } else d[j] = -1;
    }
    __syncthreads();
    int c0 = hist[2 * t], c1 = hist[2 * t + 1];
    int s2 = c0 + c1;
    __syncthreads();
    loff[t] = s2;
    __syncthreads();
    for (int off = 1; off < 256; off <<= 1) {
        int u = (t >= off) ? loff[t - off] : 0;
        __syncthreads();
        loff[t] += u;
        __syncthreads();
    }
    int excl = loff[t] - s2;
    __syncthreads();
    loff[2 * t] = excl;          loff[2 * t + 1] = excl + c0;
    lcur[2 * t] = excl;          lcur[2 * t + 1] = excl + c0;
    gbase[2 * t]     = atomicAdd(&cursor[2 * t], c0);
    gbase[2 * t + 1] = atomicAdd(&cursor[2 * t + 1], c1);
    __syncthreads();
#pragma unroll
    for (int j = 0; j < 16; ++j) {
        if (d[j] >= 0) {
            int b = d[j] / BSZ;
            int p = atomicAdd(&lcur[b], 1);
            stg[p] = make_int2(d[j], sx[j]);
        }
    }
    __syncthreads();
    for (int i = t; i < n; i += 256) {
        int2 r = stg[i];
        int b = r.x / BSZ;
        int pos = gbase[b] + (i - loff[b]);
        if (pos < (b + 1) * TCAP) tmp[pos] = r;  // overflow guard (never hit, 15 sigma)
    }
}

// ---------- bucket-base scan ----------
__global__ __launch_bounds__(512) void bscan_kernel(const int* __restrict__ cursor,
                                                    int* __restrict__ bbase,
                                                    int* __restrict__ row_ptr) {
    __shared__ int sm[512];
    int t = threadIdx.x;
    int v = (t < NBK) ? (cursor[t] - t * TCAP) : 0;
    sm[t] = v;
    __syncthreads();
    for (int off = 1; off < 512; off <<= 1) {
        int u = (t >= off) ? sm[t - off] : 0;
        __syncthreads();
        sm[t] += u;
        __syncthreads();
    }
    if (t < NBK) bbase[t] = sm[t] - v;
    if (t == 511) row_ptr[NN] = sm[511];  // == EE
}

// ---------- sort phase B: counting sort within bucket ----------
__global__ __launch_bounds__(256) void sortB_kernel(const int2* __restrict__ tmp,
                                                    const int* __restrict__ cursor,
                                                    const int* __restrict__ bbase,
                                                    float* __restrict__ dinv,
                                                    int* __restrict__ row_ptr,
                                                    int2* __restrict__ er2) {
    __shared__ int2 se[TCAP];     // 24KB
    __shared__ int2 so[TCAP];     // 24KB
    __shared__ int hist[256], lcur[256];
    int b = blockIdx.x;
    int n0 = b * BSZ;
    if (n0 >= NN) return;
    int n1 = n0 + BSZ; if (n1 > NN) n1 = NN;
    int nb = n1 - n0;
    int t = threadIdx.x;
    int cnt = cursor[b] - b * TCAP;
    int base = bbase[b];
    hist[t] = 0;
    __syncthreads();
    for (int i = t; i < cnt; i += 256) {
        int2 r = tmp[b * TCAP + i];
        se[i] = r;
        atomicAdd(&hist[r.x - n0], 1);
    }
    __syncthreads();
    if (t < nb) dinv[n0 + t] = rsqrtf((float)(hist[t] + 1));  // +1 self-loop
    int v = hist[t];
    lcur[t] = v;
    __syncthreads();
    for (int off = 1; off < 256; off <<= 1) {
        int u = (t >= off) ? lcur[t - off] : 0;
        __syncthreads();
        lcur[t] += u;
        __syncthreads();
    }
    int excl = lcur[t] - v;
    __syncthreads();
    lcur[t] = excl;
    if (t < nb) row_ptr[n0 + t] = base + excl;
    __syncthreads();
    for (int i = t; i < cnt; i += 256) {
        int2 r = se[i];
        int ln = r.x - n0;
        int pos = atomicAdd(&lcur[ln], 1);
        so[pos] = make_int2(r.y, r.x);  // (src, dst)
    }
    __syncthreads();
    for (int i = t; i < cnt; i += 256) er2[base + i] = so[i];  // coalesced
}

// ---------- weight fill ----------
__global__ __launch_bounds__(256) void wfill_kernel(const int2* __restrict__ er2,
                                                    const float* __restrict__ dinv,
                                                    int2* __restrict__ er) {
    int i = blockIdx.x * 256 + threadIdx.x;
    if (i >= EE) return;
    int2 r = er2[i];
    float w = dinv[r.y] * dinv[r.x];
    er[i] = make_int2(r.x, __float_as_int(w));
}

// ---------- projection: y0 = feat @ W^T (LDS-tiled, coalesced) ----------
__global__ __launch_bounds__(256) void proj_kernel(const float4* __restrict__ feat4,
                                                   const float* __restrict__ W,
                                                   float4* __restrict__ y0) {
    __shared__ float smW[CC * 68];   // 10.9KB
    __shared__ float smF[64 * 68];   // 17.4KB
    __shared__ float smO[64 * 42];   // 10.8KB
    int t = threadIdx.x;
    for (int j = t; j < CC * 16; j += 256) {
        int c = j >> 4, q = j & 15;
        *(float4*)(smW + c * 68 + q * 4) = ((const float4*)W)[j];
    }
    int n0 = blockIdx.x * 64;
    for (int j = t; j < 64 * 16; j += 256) {
        int r = j >> 4, q = j & 15;
        if (n0 + r < NN)
            *(float4*)(smF + r * 68 + q * 4) = feat4[(size_t)(n0 + r) * 16 + q];
    }
    __syncthreads();
    int ln = t >> 2, c0 = (t & 3) * 10;
    int node = n0 + ln;
    float acc[10];
#pragma unroll
    for (int c = 0; c < 10; ++c) acc[c] = 0.f;
    if (node < NN) {
#pragma unroll
        for (int db = 0; db < 16; ++db) {
            float4 fv = *(const float4*)(smF + ln * 68 + db * 4);
#pragma unroll
            for (int c = 0; c < 10; ++c) {
                float4 wv = *(const float4*)(smW + (c0 + c) * 68 + db * 4);
                acc[c] = fmaf(fv.x, wv.x, acc[c]);
                acc[c] = fmaf(fv.y, wv.y, acc[c]);
                acc[c] = fmaf(fv.z, wv.z, acc[c]);
                acc[c] = fmaf(fv.w, wv.w, acc[c]);
            }
        }
    }
#pragma unroll
    for (int c = 0; c < 10; ++c) smO[ln * 42 + c0 + c] = acc[c];
    __syncthreads();
    for (int j = t; j < 64 * 5; j += 256) {
        int r = j / 5, q = j - r * 5;
        if (n0 + r < NN) {
            const float* s = smO + r * 42 + q * 8;
            float4 ov;
            __half2* op = (__half2*)&ov;
            op[0] = __floats2half2_rn(s[0], s[1]);
            op[1] = __floats2half2_rn(s[2], s[3]);
            op[2] = __floats2half2_rn(s[4], s[5]);
            op[3] = __floats2half2_rn(s[6], s[7]);
            y0[(q < 4) ? ((size_t)(n0 + r) * 4 + q) : (size_t)(PL1 + n0 + r)] = ov;
        }
    }
}

// decode float4-of-8-halves into 8 floats
#define DEC8(V, F0, F1, F2, F3)                                             \
    const __half2* hp_##F0 = (const __half2*)&(V);                          \
    float2 F0 = __half22float2(hp_##F0[0]), F1 = __half22float2(hp_##F0[1]);\
    float2 F2 = __half22float2(hp_##F0[2]), F3 = __half22float2(hp_##F0[3]);

// ---------- SpMM propagate step: x_out = A_hat * x (C-space, fp16, dual-plane)
// 5 lanes/node (8 halves each), 12 nodes/wave (lanes 60-63 idle).
__global__ __launch_bounds__(256) void spmm_prop(
    const float4* __restrict__ x, float4* __restrict__ x_out,
    const int* __restrict__ row_ptr, const ERec* __restrict__ er,
    const float* __restrict__ dinv) {
    int tid = blockIdx.x * 256 + threadIdx.x;
    int wid = tid >> 6;
    int lane = tid & 63;
    int nw = lane / 5;
    int li = lane - nw * 5;
    int g = wid * 12 + nw;
    if (nw >= 12 || g >= NN) return;
    int beg = row_ptr[g], end = row_ptr[g + 1];
    float di = dinv[g];
    float w0 = di * di;
    int m = (li < 4) ? 4 : 1;
    int a = (li < 4) ? li : PL1;
    int base = g * m + a;
    float4 sv = x[base];
    float a0, a1, a2, a3, a4, a5, a6, a7;
    {
        DEC8(sv, f0, f1, f2, f3)
        a0 = w0 * f0.x; a1 = w0 * f0.y; a2 = w0 * f1.x; a3 = w0 * f1.y;
        a4 = w0 * f2.x; a5 = w0 * f2.y; a6 = w0 * f3.x; a7 = w0 * f3.y;
    }
#define ACC8(R, V)                                                          \
    {                                                                       \
        DEC8(V, f0, f1, f2, f3)                                             \
        a0 = fmaf((R).w, f0.x, a0); a1 = fmaf((R).w, f0.y, a1);             \
        a2 = fmaf((R).w, f1.x, a2); a3 = fmaf((R).w, f1.y, a3);             \
        a4 = fmaf((R).w, f2.x, a4); a5 = fmaf((R).w, f2.y, a5);             \
        a6 = fmaf((R).w, f3.x, a6); a7 = fmaf((R).w, f3.y, a7);             \
    }
    int e = beg;
    int e4 = beg + ((end - beg) & ~3);
    for (; e < e4; e += 4) {
        ERec r0 = er[e], r1 = er[e + 1], r2 = er[e + 2], r3 = er[e + 3];
        float4 v0 = x[r0.c * m + a];
        float4 v1 = x[r1.c * m + a];
        float4 v2 = x[r2.c * m + a];
        float4 v3 = x[r3.c * m + a];
        ACC8(r0, v0); ACC8(r1, v1); ACC8(r2, v2); ACC8(r3, v3);
    }
    for (; e < end; ++e) {
        ERec r = er[e];
        float4 v = x[r.c * m + a];
        ACC8(r, v);
    }
    float4 ov;
    __half2* op = (__half2*)&ov;
    op[0] = __floats2half2_rn(a0, a1);
    op[1] = __floats2half2_rn(a2, a3);
    op[2] = __floats2half2_rn(a4, a5);
    op[3] = __floats2half2_rn(a6, a7);
    x_out[base] = ov;
#undef ACC8
}

// ---------- final step: acc = A*x15 (= x16), then
// out = C16*x16 + C15*x15 + C14*x14 + C13*x13 + C12*x12 + C11*x11
//       + (0.05/15)*y0 + bias            (c_k = 0.95/16^(17-k); k<=10 ~ 1e-8)
__global__ __launch_bounds__(256) void spmm_final(
    const float4* __restrict__ x,     // x15 (gather source)
    const float4* __restrict__ xk0,   // x11
    const float4* __restrict__ xk1,   // x12
    const float4* __restrict__ xk2,   // x13
    const float4* __restrict__ xk3,   // x14
    const float4* __restrict__ y0,
    const float* __restrict__ bias,
    const int* __restrict__ row_ptr, const ERec* __restrict__ er,
    const float* __restrict__ dinv, float* __restrict__ outp) {
    int tid = blockIdx.x * 256 + threadIdx.x;
    int wid = tid >> 6;
    int lane = tid & 63;
    int nw = lane / 5;
    int li = lane - nw * 5;
    int g = wid * 12 + nw;
    if (nw >= 12 || g >= NN) return;
    int beg = row_ptr[g], end = row_ptr[g + 1];
    float di = dinv[g];
    float w0 = di * di;
    int m = (li < 4) ? 4 : 1;
    int a = (li < 4) ? li : PL1;
    int base = g * m + a;
    float4 sv = x[base];
    float s0, s1, s2, s3, s4, s5, s6, s7;
    float a0, a1, a2, a3, a4, a5, a6, a7;
    {
        DEC8(sv, f0, f1, f2, f3)
        s0 = f0.x; s1 = f0.y; s2 = f1.x; s3 = f1.y;
        s4 = f2.x; s5 = f2.y; s6 = f3.x; s7 = f3.y;
        a0 = w0 * s0; a1 = w0 * s1; a2 = w0 * s2; a3 = w0 * s3;
        a4 = w0 * s4; a5 = w0 * s5; a6 = w0 * s6; a7 = w0 * s7;
    }
#define ACC8(R, V)                                                          \
    {                                                                       \
        DEC8(V, f0, f1, f2, f3)                                             \
        a0 = fmaf((R).w, f0.x, a0); a1 = fmaf((R).w, f0.y, a1);             \
        a2 = fmaf((R).w, f1.x, a2); a3 = fmaf((R).w, f1.y, a3);             \
        a4 = fmaf((R).w, f2.x, a4); a5 = fmaf((R).w, f2.y, a5);             \
        a6 = fmaf((R).w, f3.x, a6); a7 = fmaf((R).w, f3.y, a7);             \
    }
    int e = beg;
    int e4 = beg + ((end - beg) & ~3);
    for (; e < e4; e += 4) {
        ERec r0 = er[e], r1 = er[e + 1], r2 = er[e + 2], r3 = er[e + 3];
        float4 v0 = x[r0.c * m + a];
        float4 v1 = x[r1.c * m + a];
        float4 v2 = x[r2.c * m + a];
        float4 v3 = x[r3.c * m + a];
        ACC8(r0, v0); ACC8(r1, v1); ACC8(r2, v2); ACC8(r3, v3);
    }
    for (; e < end; ++e) {
        ERec r = er[e];
        float4 v = x[r.c * m + a];
        ACC8(r, v);
    }
#undef ACC8
    const float C16 = 0.95f / 16.0f;
    const float C15 = 0.95f / 256.0f;
    const float C14 = 0.95f / 4096.0f;
    const float C13 = 0.95f / 65536.0f;
    const float C12 = 0.95f / 1048576.0f;
    const float C11 = 0.95f / 16777216.0f;
    const float FC  = 0.05f / 15.0f;
    float o0 = C16 * a0 + C15 * s0, o1 = C16 * a1 + C15 * s1;
    float o2 = C16 * a2 + C15 * s2, o3 = C16 * a3 + C15 * s3;
    float o4 = C16 * a4 + C15 * s4, o5 = C16 * a5 + C15 * s5;
    float o6 = C16 * a6 + C15 * s6, o7 = C16 * a7 + C15 * s7;
#define ADD8(P, CF)                                                         \
    {                                                                       \
        float4 v = (P)[base];                                               \
        DEC8(v, f0, f1, f2, f3)                                             \
        o0 = fmaf((CF), f0.x, o0); o1 = fmaf((CF), f0.y, o1);               \
        o2 = fmaf((CF), f1.x, o2); o3 = fmaf((CF), f1.y, o3);               \
        o4 = fmaf((CF), f2.x, o4); o5 = fmaf((CF), f2.y, o5);               \
        o6 = fmaf((CF), f3.x, o6); o7 = fmaf((CF), f3.y, o7);               \
    }
    ADD8(xk3, C14)
    ADD8(xk2, C13)
    ADD8(xk1, C12)
    ADD8(xk0, C11)
    ADD8(y0, FC)
#undef ADD8
    const float4* b4 = (const float4*)(bias + li * 8);
    float4 bb0 = b4[0], bb1 = b4[1];
    float4 w0v = make_float4(o0 + bb0.x, o1 + bb0.y, o2 + bb0.z, o3 + bb0.w);
    float4 w1v = make_float4(o4 + bb1.x, o5 + bb1.y, o6 + bb1.z, o7 + bb1.w);
    float4* op = (float4*)(outp + (size_t)g * CC + li * 8);
    op[0] = w0v; op[1] = w1v;
}

extern "C" void kernel_launch(void* const* d_in, const int* in_sizes, int n_in,
                              void* d_out, int out_size, void* d_ws, size_t ws_size,
                              hipStream_t stream) {
    const float* feat = (const float*)d_in[0];
    const float* W    = (const float*)d_in[1];
    const float* b    = (const float*)d_in[2];
    const int*   src  = (const int*)d_in[3];
    const int*   dst  = (const int*)d_in[4];
    float* out = (float*)d_out;

    char* p = (char*)d_ws;
    auto alloc = [&](size_t bytes) {
        char* r = p;
        p += (bytes + 255) & ~(size_t)255;
        return r;
    };
    float*   dinv    = (float*)alloc((size_t)NN * sizeof(float));
    int*     row_ptr = (int*)alloc((size_t)(NN + 1) * sizeof(int));
    int*     cursor  = (int*)alloc((size_t)NBK * sizeof(int));
    int*     bbase   = (int*)alloc((size_t)NBK * sizeof(int));
    int2*    tmp     = (int2*)alloc((size_t)NBK * TCAP * sizeof(int2));  // 12.6MB
    int2*    er2     = (int2*)alloc((size_t)EE * sizeof(int2));          // 9.6MB
    int2*    er      = (int2*)alloc((size_t)EE * sizeof(int2));          // 9.6MB
    float4*  y0      = (float4*)alloc((size_t)NN * 5 * sizeof(float4));  // 8MB
    float4*  xa      = (float4*)alloc((size_t)NN * 5 * sizeof(float4));  // 8MB
    float4*  xb      = (float4*)alloc((size_t)NN * 5 * sizeof(float4));  // 8MB
    float4*  xk2b    = (float4*)alloc((size_t)NN * 5 * sizeof(float4));  // 8MB
    float4*  xk3b    = (float4*)alloc((size_t)NN * 5 * sizeof(float4));  // 8MB
    float4*  xk4b    = (float4*)alloc((size_t)NN * 5 * sizeof(float4));  // 8MB
    // alias xk0/xk1 over tmp/er2 (dead after sortB/wfill; both >= 8MB)
    float4*  xk0b    = (float4*)tmp;
    float4*  xk1b    = (float4*)er2;

    curinit_kernel<<<1, 512, 0, stream>>>(cursor);
    sortA_kernel<<<ABLK, 256, 0, stream>>>(src, dst, cursor, tmp);
    bscan_kernel<<<1, 512, 0, stream>>>(cursor, bbase, row_ptr);
    sortB_kernel<<<NBK, 256, 0, stream>>>(tmp, cursor, bbase, dinv, row_ptr, er2);
    wfill_kernel<<<(EE + 255) / 256, 256, 0, stream>>>(er2, dinv, er);
    proj_kernel<<<(NN + 63) / 64, 256, 0, stream>>>((const float4*)feat, W, y0);

    const int SPMM_BLOCKS = (8334 + 3) / 4;  // ceil(ceil(NN/12)/4) = 2084
    // j = 0..9: ping-pong xa/xb (x1..x10, not needed later)
    const float4* xs = y0;
    for (int j = 0; j < 10; ++j) {
        float4* xd = (j & 1) ? xb : xa;
        spmm_prop<<<SPMM_BLOCKS, 256, 0, stream>>>(xs, xd, row_ptr,
                                                   (const ERec*)er, dinv);
        xs = xd;
    }
    // j = 10..14: write x11..x15 into preserved buffers
    float4* xk[5] = {xk0b, xk1b, xk2b, xk3b, xk4b};
    for (int s = 0; s < 5; ++s) {
        spmm_prop<<<SPMM_BLOCKS, 256, 0, stream>>>(xs, xk[s], row_ptr,
                                                   (const ERec*)er, dinv);
        xs = xk[s];
    }
    // final: acc = A*x15, combine all terms -> out
    spmm_final<<<SPMM_BLOCKS, 256, 0, stream>>>(xk4b, xk0b, xk1b, xk2b, xk3b,
                                                y0, b, row_ptr, (const ERec*)er,
                                                dinv, out);
}

// Round 11
// 582.158 us; speedup vs baseline: 1.3137x; 1.0529x over previous
//
#include <hip/hip_runtime.h>
#include <hip/hip_fp16.h>

#define NN 100000
#define EE 1200000
#define DD 64
#define CC 40
#define KK 16
#define BSZ 196                          // nodes per sort bucket
#define NBK 512                          // buckets (512*196 = 100352 >= NN)
#define TCAP 3072                        // tmp capacity per bucket (mean 2352, ~15 sigma)
#define EPB 4096                         // edges per phase-A block
#define ABLK ((EE + EPB - 1) / EPB)      // 293
#define PL1 (NN * 4)                     // float4-index offset of plane1 in an x buffer
#define GBLK ((NN + 11) / 12)            // 8334 one-wave spmm blocks

struct __align__(8) ERec { int c; float w; };

// ---------- cursor init: cursor[b] = b*TCAP ----------
__global__ __launch_bounds__(512) void curinit_kernel(int* __restrict__ cursor) {
    int b = threadIdx.x;
    if (b < NBK) cursor[b] = b * TCAP;
}

// ---------- sort phase A: LDS-bin 4096 edges into 512 buckets, write runs ----------
__global__ __launch_bounds__(256) void sortA_kernel(const int* __restrict__ src,
                                                    const int* __restrict__ dst,
                                                    int* __restrict__ cursor,
                                                    int2* __restrict__ tmp) {
    __shared__ int2 stg[EPB];                 // 32KB
    __shared__ int hist[NBK], loff[NBK], lcur[NBK], gbase[NBK];  // 8KB
    int t = threadIdx.x;
    long e0 = (long)blockIdx.x * EPB;
    int n = (int)((EE - e0 < EPB) ? (EE - e0) : EPB);
    for (int j = t; j < NBK; j += 256) hist[j] = 0;
    __syncthreads();
    int d[16], sx[16];
#pragma unroll
    for (int j = 0; j < 16; ++j) {
        int i = t + j * 256;
        if (i < n) {
            d[j] = dst[e0 + i];
            sx[j] = src[e0 + i];
            atomicAdd(&hist[d[j] / BSZ], 1);
        } else d[j] = -1;
    }
    __syncthreads();
    int c0 = hist[2 * t], c1 = hist[2 * t + 1];
    int s2 = c0 + c1;
    __syncthreads();
    loff[t] = s2;
    __syncthreads();
    for (int off = 1; off < 256; off <<= 1) {
        int u = (t >= off) ? loff[t - off] : 0;
        __syncthreads();
        loff[t] += u;
        __syncthreads();
    }
    int excl = loff[t] - s2;
    __syncthreads();
    loff[2 * t] = excl;          loff[2 * t + 1] = excl + c0;
    lcur[2 * t] = excl;          lcur[2 * t + 1] = excl + c0;
    gbase[2 * t]     = atomicAdd(&cursor[2 * t], c0);
    gbase[2 * t + 1] = atomicAdd(&cursor[2 * t + 1], c1);
    __syncthreads();
#pragma unroll
    for (int j = 0; j < 16; ++j) {
        if (d[j] >= 0) {
            int b = d[j] / BSZ;
            int p = atomicAdd(&lcur[b], 1);
            stg[p] = make_int2(d[j], sx[j]);
        }
    }
    __syncthreads();
    for (int i = t; i < n; i += 256) {
        int2 r = stg[i];
        int b = r.x / BSZ;
        int pos = gbase[b] + (i - loff[b]);
        if (pos < (b + 1) * TCAP) tmp[pos] = r;  // overflow guard (never hit, 15 sigma)
    }
}

// ---------- bucket-base scan ----------
__global__ __launch_bounds__(512) void bscan_kernel(const int* __restrict__ cursor,
                                                    int* __restrict__ bbase,
                                                    int* __restrict__ row_ptr) {
    __shared__ int sm[512];
    int t = threadIdx.x;
    int v = (t < NBK) ? (cursor[t] - t * TCAP) : 0;
    sm[t] = v;
    __syncthreads();
    for (int off = 1; off < 512; off <<= 1) {
        int u = (t >= off) ? sm[t - off] : 0;
        __syncthreads();
        sm[t] += u;
        __syncthreads();
    }
    if (t < NBK) bbase[t] = sm[t] - v;
    if (t == 511) row_ptr[NN] = sm[511];  // == EE
}

// ---------- sort phase B: counting sort within bucket ----------
__global__ __launch_bounds__(256) void sortB_kernel(const int2* __restrict__ tmp,
                                                    const int* __restrict__ cursor,
                                                    const int* __restrict__ bbase,
                                                    float* __restrict__ dinv,
                                                    int* __restrict__ row_ptr,
                                                    int2* __restrict__ er2) {
    __shared__ int2 se[TCAP];     // 24KB
    __shared__ int2 so[TCAP];     // 24KB
    __shared__ int hist[256], lcur[256];
    int b = blockIdx.x;
    int n0 = b * BSZ;
    if (n0 >= NN) return;
    int n1 = n0 + BSZ; if (n1 > NN) n1 = NN;
    int nb = n1 - n0;
    int t = threadIdx.x;
    int cnt = cursor[b] - b * TCAP;
    int base = bbase[b];
    hist[t] = 0;
    __syncthreads();
    for (int i = t; i < cnt; i += 256) {
        int2 r = tmp[b * TCAP + i];
        se[i] = r;
        atomicAdd(&hist[r.x - n0], 1);
    }
    __syncthreads();
    if (t < nb) dinv[n0 + t] = rsqrtf((float)(hist[t] + 1));  // +1 self-loop
    int v = hist[t];
    lcur[t] = v;
    __syncthreads();
    for (int off = 1; off < 256; off <<= 1) {
        int u = (t >= off) ? lcur[t - off] : 0;
        __syncthreads();
        lcur[t] += u;
        __syncthreads();
    }
    int excl = lcur[t] - v;
    __syncthreads();
    lcur[t] = excl;
    if (t < nb) row_ptr[n0 + t] = base + excl;
    __syncthreads();
    for (int i = t; i < cnt; i += 256) {
        int2 r = se[i];
        int ln = r.x - n0;
        int pos = atomicAdd(&lcur[ln], 1);
        so[pos] = make_int2(r.y, r.x);  // (src, dst)
    }
    __syncthreads();
    for (int i = t; i < cnt; i += 256) er2[base + i] = so[i];  // coalesced
}

// ---------- weight fill ----------
__global__ __launch_bounds__(256) void wfill_kernel(const int2* __restrict__ er2,
                                                    const float* __restrict__ dinv,
                                                    int2* __restrict__ er) {
    int i = blockIdx.x * 256 + threadIdx.x;
    if (i >= EE) return;
    int2 r = er2[i];
    float w = dinv[r.y] * dinv[r.x];
    er[i] = make_int2(r.x, __float_as_int(w));
}

// ---------- projection: y0 = feat @ W^T (LDS-tiled, coalesced) ----------
__global__ __launch_bounds__(256) void proj_kernel(const float4* __restrict__ feat4,
                                                   const float* __restrict__ W,
                                                   float4* __restrict__ y0) {
    __shared__ float smW[CC * 68];   // 10.9KB
    __shared__ float smF[64 * 68];   // 17.4KB
    __shared__ float smO[64 * 42];   // 10.8KB
    int t = threadIdx.x;
    for (int j = t; j < CC * 16; j += 256) {
        int c = j >> 4, q = j & 15;
        *(float4*)(smW + c * 68 + q * 4) = ((const float4*)W)[j];
    }
    int n0 = blockIdx.x * 64;
    for (int j = t; j < 64 * 16; j += 256) {
        int r = j >> 4, q = j & 15;
        if (n0 + r < NN)
            *(float4*)(smF + r * 68 + q * 4) = feat4[(size_t)(n0 + r) * 16 + q];
    }
    __syncthreads();
    int ln = t >> 2, c0 = (t & 3) * 10;
    int node = n0 + ln;
    float acc[10];
#pragma unroll
    for (int c = 0; c < 10; ++c) acc[c] = 0.f;
    if (node < NN) {
#pragma unroll
        for (int db = 0; db < 16; ++db) {
            float4 fv = *(const float4*)(smF + ln * 68 + db * 4);
#pragma unroll
            for (int c = 0; c < 10; ++c) {
                float4 wv = *(const float4*)(smW + (c0 + c) * 68 + db * 4);
                acc[c] = fmaf(fv.x, wv.x, acc[c]);
                acc[c] = fmaf(fv.y, wv.y, acc[c]);
                acc[c] = fmaf(fv.z, wv.z, acc[c]);
                acc[c] = fmaf(fv.w, wv.w, acc[c]);
            }
        }
    }
#pragma unroll
    for (int c = 0; c < 10; ++c) smO[ln * 42 + c0 + c] = acc[c];
    __syncthreads();
    for (int j = t; j < 64 * 5; j += 256) {
        int r = j / 5, q = j - r * 5;
        if (n0 + r < NN) {
            const float* s = smO + r * 42 + q * 8;
            float4 ov;
            __half2* op = (__half2*)&ov;
            op[0] = __floats2half2_rn(s[0], s[1]);
            op[1] = __floats2half2_rn(s[2], s[3]);
            op[2] = __floats2half2_rn(s[4], s[5]);
            op[3] = __floats2half2_rn(s[6], s[7]);
            y0[(q < 4) ? ((size_t)(n0 + r) * 4 + q) : (size_t)(PL1 + n0 + r)] = ov;
        }
    }
}

// decode float4-of-8-halves into 8 floats
#define DEC8(V, F0, F1, F2, F3)                                             \
    const __half2* hp_##F0 = (const __half2*)&(V);                          \
    float2 F0 = __half22float2(hp_##F0[0]), F1 = __half22float2(hp_##F0[1]);\
    float2 F2 = __half22float2(hp_##F0[2]), F3 = __half22float2(hp_##F0[3]);

#define ACC8(R, V)                                                          \
    {                                                                       \
        DEC8(V, f0, f1, f2, f3)                                             \
        a0 = fmaf((R).w, f0.x, a0); a1 = fmaf((R).w, f0.y, a1);             \
        a2 = fmaf((R).w, f1.x, a2); a3 = fmaf((R).w, f1.y, a3);             \
        a4 = fmaf((R).w, f2.x, a4); a5 = fmaf((R).w, f2.y, a5);             \
        a6 = fmaf((R).w, f3.x, a6); a7 = fmaf((R).w, f3.y, a7);             \
    }

// edge loop, unroll x8 then x4 then singles — up to 8 gathers in flight/lane
#define EDGE_LOOP                                                           \
    int e = beg;                                                            \
    int e8 = beg + ((end - beg) & ~7);                                      \
    for (; e < e8; e += 8) {                                                \
        ERec r0 = er[e], r1 = er[e + 1], r2 = er[e + 2], r3 = er[e + 3];    \
        ERec r4 = er[e + 4], r5 = er[e + 5], r6 = er[e + 6], r7 = er[e + 7];\
        float4 v0 = x[r0.c * m + a];                                        \
        float4 v1 = x[r1.c * m + a];                                        \
        float4 v2 = x[r2.c * m + a];                                        \
        float4 v3 = x[r3.c * m + a];                                        \
        float4 v4 = x[r4.c * m + a];                                        \
        float4 v5 = x[r5.c * m + a];                                        \
        float4 v6 = x[r6.c * m + a];                                        \
        float4 v7 = x[r7.c * m + a];                                        \
        ACC8(r0, v0); ACC8(r1, v1); ACC8(r2, v2); ACC8(r3, v3);             \
        ACC8(r4, v4); ACC8(r5, v5); ACC8(r6, v6); ACC8(r7, v7);             \
    }                                                                       \
    int e4 = e + ((end - e) & ~3);                                          \
    for (; e < e4; e += 4) {                                                \
        ERec r0 = er[e], r1 = er[e + 1], r2 = er[e + 2], r3 = er[e + 3];    \
        float4 v0 = x[r0.c * m + a];                                        \
        float4 v1 = x[r1.c * m + a];                                        \
        float4 v2 = x[r2.c * m + a];                                        \
        float4 v3 = x[r3.c * m + a];                                        \
        ACC8(r0, v0); ACC8(r1, v1); ACC8(r2, v2); ACC8(r3, v3);             \
    }                                                                       \
    for (; e < end; ++e) {                                                  \
        ERec r = er[e];                                                     \
        float4 v = x[r.c * m + a];                                          \
        ACC8(r, v);                                                         \
    }

// ---------- SpMM propagate step: x_out = A_hat * x (C-space, fp16, dual-plane)
// one wave per block (12 nodes, 5 lanes each; lanes 60-63 idle) — fine-grained
// blocks for load balance; unroll x8 for gather MLP.
__global__ __launch_bounds__(64) void spmm_prop(
    const float4* __restrict__ x, float4* __restrict__ x_out,
    const int* __restrict__ row_ptr, const ERec* __restrict__ er,
    const float* __restrict__ dinv) {
    int lane = threadIdx.x;
    int nw = lane / 5;
    int li = lane - nw * 5;
    int g = blockIdx.x * 12 + nw;
    if (nw >= 12 || g >= NN) return;
    int beg = row_ptr[g], end = row_ptr[g + 1];
    float di = dinv[g];
    float w0 = di * di;
    int m = (li < 4) ? 4 : 1;
    int a = (li < 4) ? li : PL1;
    int base = g * m + a;
    float4 sv = x[base];
    float a0, a1, a2, a3, a4, a5, a6, a7;
    {
        DEC8(sv, f0, f1, f2, f3)
        a0 = w0 * f0.x; a1 = w0 * f0.y; a2 = w0 * f1.x; a3 = w0 * f1.y;
        a4 = w0 * f2.x; a5 = w0 * f2.y; a6 = w0 * f3.x; a7 = w0 * f3.y;
    }
    EDGE_LOOP
    float4 ov;
    __half2* op = (__half2*)&ov;
    op[0] = __floats2half2_rn(a0, a1);
    op[1] = __floats2half2_rn(a2, a3);
    op[2] = __floats2half2_rn(a4, a5);
    op[3] = __floats2half2_rn(a6, a7);
    x_out[base] = ov;
}

// ---------- final step: acc = A*x15 (= x16), then
// out = C16*x16 + C15*x15 + C14*x14 + C13*x13 + FC*y0 + bias
// (c_k = 0.95/16^(17-k); k<=12 terms <= ~3e-6 -> dropped)
__global__ __launch_bounds__(64) void spmm_final(
    const float4* __restrict__ x,     // x15 (gather source)
    const float4* __restrict__ x13p,
    const float4* __restrict__ x14p,
    const float4* __restrict__ y0,
    const float* __restrict__ bias,
    const int* __restrict__ row_ptr, const ERec* __restrict__ er,
    const float* __restrict__ dinv, float* __restrict__ outp) {
    int lane = threadIdx.x;
    int nw = lane / 5;
    int li = lane - nw * 5;
    int g = blockIdx.x * 12 + nw;
    if (nw >= 12 || g >= NN) return;
    int beg = row_ptr[g], end = row_ptr[g + 1];
    float di = dinv[g];
    float w0 = di * di;
    int m = (li < 4) ? 4 : 1;
    int a = (li < 4) ? li : PL1;
    int base = g * m + a;
    float4 sv = x[base];
    float s0, s1, s2, s3, s4, s5, s6, s7;
    float a0, a1, a2, a3, a4, a5, a6, a7;
    {
        DEC8(sv, f0, f1, f2, f3)
        s0 = f0.x; s1 = f0.y; s2 = f1.x; s3 = f1.y;
        s4 = f2.x; s5 = f2.y; s6 = f3.x; s7 = f3.y;
        a0 = w0 * s0; a1 = w0 * s1; a2 = w0 * s2; a3 = w0 * s3;
        a4 = w0 * s4; a5 = w0 * s5; a6 = w0 * s6; a7 = w0 * s7;
    }
    EDGE_LOOP
    const float C16 = 0.95f / 16.0f;
    const float C15 = 0.95f / 256.0f;
    const float C14 = 0.95f / 4096.0f;
    const float C13 = 0.95f / 65536.0f;
    const float FC  = 0.05f / 15.0f;
    float o0 = C16 * a0 + C15 * s0, o1 = C16 * a1 + C15 * s1;
    float o2 = C16 * a2 + C15 * s2, o3 = C16 * a3 + C15 * s3;
    float o4 = C16 * a4 + C15 * s4, o5 = C16 * a5 + C15 * s5;
    float o6 = C16 * a6 + C15 * s6, o7 = C16 * a7 + C15 * s7;
#define ADD8(P, CF)                                                         \
    {                                                                       \
        float4 v = (P)[base];                                               \
        DEC8(v, f0, f1, f2, f3)                                             \
        o0 = fmaf((CF), f0.x, o0); o1 = fmaf((CF), f0.y, o1);               \
        o2 = fmaf((CF), f1.x, o2); o3 = fmaf((CF), f1.y, o3);               \
        o4 = fmaf((CF), f2.x, o4); o5 = fmaf((CF), f2.y, o5);               \
        o6 = fmaf((CF), f3.x, o6); o7 = fmaf((CF), f3.y, o7);               \
    }
    ADD8(x14p, C14)
    ADD8(x13p, C13)
    ADD8(y0, FC)
#undef ADD8
    const float4* b4 = (const float4*)(bias + li * 8);
    float4 bb0 = b4[0], bb1 = b4[1];
    float4 w0v = make_float4(o0 + bb0.x, o1 + bb0.y, o2 + bb0.z, o3 + bb0.w);
    float4 w1v = make_float4(o4 + bb1.x, o5 + bb1.y, o6 + bb1.z, o7 + bb1.w);
    float4* op = (float4*)(outp + (size_t)g * CC + li * 8);
    op[0] = w0v; op[1] = w1v;
}

extern "C" void kernel_launch(void* const* d_in, const int* in_sizes, int n_in,
                              void* d_out, int out_size, void* d_ws, size_t ws_size,
                              hipStream_t stream) {
    const float* feat = (const float*)d_in[0];
    const float* W    = (const float*)d_in[1];
    const float* b    = (const float*)d_in[2];
    const int*   src  = (const int*)d_in[3];
    const int*   dst  = (const int*)d_in[4];
    float* out = (float*)d_out;

    char* p = (char*)d_ws;
    auto alloc = [&](size_t bytes) {
        char* r = p;
        p += (bytes + 255) & ~(size_t)255;
        return r;
    };
    float*   dinv    = (float*)alloc((size_t)NN * sizeof(float));
    int*     row_ptr = (int*)alloc((size_t)(NN + 1) * sizeof(int));
    int*     cursor  = (int*)alloc((size_t)NBK * sizeof(int));
    int*     bbase   = (int*)alloc((size_t)NBK * sizeof(int));
    int2*    tmp     = (int2*)alloc((size_t)NBK * TCAP * sizeof(int2));  // 12.6MB
    int2*    er2     = (int2*)alloc((size_t)EE * sizeof(int2));          // 9.6MB
    int2*    er      = (int2*)alloc((size_t)EE * sizeof(int2));          // 9.6MB
    float4*  y0      = (float4*)alloc((size_t)NN * 5 * sizeof(float4));  // 8MB
    float4*  xa      = (float4*)alloc((size_t)NN * 5 * sizeof(float4));  // 8MB
    float4*  xb      = (float4*)alloc((size_t)NN * 5 * sizeof(float4));  // 8MB
    float4*  x13b    = (float4*)alloc((size_t)NN * 5 * sizeof(float4));  // 8MB
    float4*  x14b    = (float4*)alloc((size_t)NN * 5 * sizeof(float4));  // 8MB
    float4*  x15b    = (float4*)alloc((size_t)NN * 5 * sizeof(float4));  // 8MB

    curinit_kernel<<<1, 512, 0, stream>>>(cursor);
    sortA_kernel<<<ABLK, 256, 0, stream>>>(src, dst, cursor, tmp);
    bscan_kernel<<<1, 512, 0, stream>>>(cursor, bbase, row_ptr);
    sortB_kernel<<<NBK, 256, 0, stream>>>(tmp, cursor, bbase, dinv, row_ptr, er2);
    wfill_kernel<<<(EE + 255) / 256, 256, 0, stream>>>(er2, dinv, er);
    proj_kernel<<<(NN + 63) / 64, 256, 0, stream>>>((const float4*)feat, W, y0);

    // j = 0..11: ping-pong xa/xb (produce x1..x12; x<=12 don't feed the output)
    const float4* xs = y0;
    for (int j = 0; j < 12; ++j) {
        float4* xd = (j & 1) ? xb : xa;
        spmm_prop<<<GBLK, 64, 0, stream>>>(xs, xd, row_ptr, (const ERec*)er, dinv);
        xs = xd;
    }
    // x13, x14, x15 into preserved buffers
    spmm_prop<<<GBLK, 64, 0, stream>>>(xs, x13b, row_ptr, (const ERec*)er, dinv);
    spmm_prop<<<GBLK, 64, 0, stream>>>(x13b, x14b, row_ptr, (const ERec*)er, dinv);
    spmm_prop<<<GBLK, 64, 0, stream>>>(x14b, x15b, row_ptr, (const ERec*)er, dinv);
    // final: acc = A*x15 (=x16), combine x16,x15,x14,x13,y0,bias -> out
    spmm_final<<<GBLK, 64, 0, stream>>>(x15b, x13b, x14b, y0, b, row_ptr,
                                        (const ERec*)er, dinv, out);
}